// Round 1
// baseline (685.629 us; speedup 1.0000x reference)
//
#include <hip/hip_runtime.h>
#include <hip/hip_bf16.h>

#define C_DIM 256
#define HEADS 8
#define HEAD_DIM 32
#define ATT_SCALE 0.17677669529663687f
#define TI 8   // i-tile rows per attention block

// ---------------------------------------------------------------------------
// K1: fused downsample + QKV GEMM.
// qkv[b,o,n] = sum_c w_qkv[o,c] * x[b,c,2h,2w],  n = h*32+w, o<768, n<1024
// 64x64 tile per block, 256 threads, 4x4 microtile, K-chunks of 32.
// ---------------------------------------------------------------------------
__global__ __launch_bounds__(256) void qkv_gemm_k(const float* __restrict__ x,
                                                  const float* __restrict__ w,
                                                  float* __restrict__ qkv) {
    int b = blockIdx.z;
    int otile = blockIdx.y * 64;
    int ntile = blockIdx.x * 64;
    __shared__ float As[32][65];  // [kk][oo]
    __shared__ float Bs[32][65];  // [kk][nn]
    float acc[4][4] = {};
    int tx = threadIdx.x & 15, ty = threadIdx.x >> 4;
    const float* xb = x + (size_t)b * 256 * 4096;

    for (int kc = 0; kc < 256; kc += 32) {
        for (int idx = threadIdx.x; idx < 2048; idx += 256) {
            int kk = idx >> 6, oo = idx & 63;
            As[kk][oo] = w[(size_t)(otile + oo) * 256 + kc + kk];
        }
        for (int idx = threadIdx.x; idx < 2048; idx += 256) {
            int kk = idx >> 6, nn = idx & 63;
            int n = ntile + nn;
            // xs[c][n] = x[b, c, 2*(n/32), 2*(n%32)]
            Bs[kk][nn] = xb[(size_t)(kc + kk) * 4096 + (n >> 5) * 128 + 2 * (n & 31)];
        }
        __syncthreads();
#pragma unroll
        for (int kk = 0; kk < 32; ++kk) {
            float a[4], bv[4];
#pragma unroll
            for (int i = 0; i < 4; ++i) a[i] = As[kk][ty * 4 + i];
#pragma unroll
            for (int j = 0; j < 4; ++j) bv[j] = Bs[kk][tx * 4 + j];
#pragma unroll
            for (int i = 0; i < 4; ++i)
#pragma unroll
                for (int j = 0; j < 4; ++j) acc[i][j] += a[i] * bv[j];
        }
        __syncthreads();
    }
#pragma unroll
    for (int i = 0; i < 4; ++i) {
        int o = otile + ty * 4 + i;
#pragma unroll
        for (int j = 0; j < 4; ++j)
            qkv[((size_t)b * 768 + o) * 1024 + ntile + tx * 4 + j] = acc[i][j];
    }
}

// ---------------------------------------------------------------------------
// K2: attention. One block per (b, h, i-tile of TI=8 rows). 256 threads.
// q,k,v laid out [b][h*96 + row][n] inside qkv (row 0-31 q, 32-63 k, 64-95 v).
// ---------------------------------------------------------------------------
__global__ __launch_bounds__(256) void attn_k(const float* __restrict__ qkv,
                                              float* __restrict__ out) {
    int itile = blockIdx.x * TI;
    int h = blockIdx.y, b = blockIdx.z;
    const float* qb = qkv + ((size_t)(b * 768 + h * 96)) * 1024;
    const float* kb = qb + 32 * 1024;
    const float* vb = qb + 64 * 1024;

    __shared__ float qs[32][TI];
    __shared__ float p[TI][1024];
    __shared__ float vs[32][65];
    __shared__ float invs[TI];

    int tid = threadIdx.x;
    int lane = tid & 63, wave = tid >> 6;

    // load q tile: 32*TI = 256 elements, one per thread
    {
        int d = tid >> 3, ii = tid & 7;
        qs[d][ii] = qb[(size_t)d * 1024 + itile + ii];
    }
    __syncthreads();

    // scores: thread owns 4 j-columns (j = tid + jj*256) for all TI rows
    {
        float acc[4][TI];
#pragma unroll
        for (int jj = 0; jj < 4; ++jj)
#pragma unroll
            for (int ii = 0; ii < TI; ++ii) acc[jj][ii] = 0.f;
        for (int d = 0; d < 32; ++d) {
            float kv[4];
#pragma unroll
            for (int jj = 0; jj < 4; ++jj) kv[jj] = kb[(size_t)d * 1024 + tid + jj * 256];
#pragma unroll
            for (int jj = 0; jj < 4; ++jj)
#pragma unroll
                for (int ii = 0; ii < TI; ++ii) acc[jj][ii] += kv[jj] * qs[d][ii];
        }
#pragma unroll
        for (int jj = 0; jj < 4; ++jj)
#pragma unroll
            for (int ii = 0; ii < TI; ++ii) p[ii][tid + jj * 256] = acc[jj][ii] * ATT_SCALE;
    }
    __syncthreads();

    // softmax per row; wave w handles rows w*2, w*2+1
#pragma unroll
    for (int r = 0; r < 2; ++r) {
        int ii = wave * 2 + r;
        float m = -3.4e38f;
#pragma unroll
        for (int t = 0; t < 16; ++t) m = fmaxf(m, p[ii][lane + t * 64]);
#pragma unroll
        for (int o = 1; o < 64; o <<= 1) m = fmaxf(m, __shfl_xor(m, o));
        float sum = 0.f;
#pragma unroll
        for (int t = 0; t < 16; ++t) {
            float e = __expf(p[ii][lane + t * 64] - m);
            p[ii][lane + t * 64] = e;
            sum += e;
        }
#pragma unroll
        for (int o = 1; o < 64; o <<= 1) sum += __shfl_xor(sum, o);
        if (lane == 0) invs[ii] = 1.f / sum;
    }
    __syncthreads();

    // PV: out_tile[32][TI]; thread owns (d = tid&31, ii = tid>>5)
    {
        int d = tid & 31, ii = tid >> 5;
        float o = 0.f;
        for (int j0 = 0; j0 < 1024; j0 += 64) {
            for (int idx = tid; idx < 2048; idx += 256) {
                int dd = idx >> 6, kk = idx & 63;
                vs[dd][kk] = vb[(size_t)dd * 1024 + j0 + kk];
            }
            __syncthreads();
#pragma unroll
            for (int kk = 0; kk < 64; ++kk) o += vs[d][kk] * p[ii][j0 + kk];
            __syncthreads();
        }
        out[((size_t)b * 256 + h * 32 + d) * 1024 + itile + ii] = o * invs[ii];
    }
}

// ---------------------------------------------------------------------------
// K3: per-(b,c) sum and sum-of-squares of attention output (1024 elements)
// ---------------------------------------------------------------------------
__global__ __launch_bounds__(256) void colsum_k(const float* __restrict__ ao,
                                                float* __restrict__ s1,
                                                float* __restrict__ s2) {
    int bc = blockIdx.x;
    const float* pp = ao + (size_t)bc * 1024;
    int tid = threadIdx.x;
    float v0 = pp[tid], v1 = pp[tid + 256], v2 = pp[tid + 512], v3 = pp[tid + 768];
    float sum = v0 + v1 + v2 + v3;
    float sq = v0 * v0 + v1 * v1 + v2 * v2 + v3 * v3;
#pragma unroll
    for (int o = 1; o < 64; o <<= 1) {
        sum += __shfl_xor(sum, o);
        sq += __shfl_xor(sq, o);
    }
    __shared__ float r1[4], r2[4];
    int lane = tid & 63, wave = tid >> 6;
    if (lane == 0) { r1[wave] = sum; r2[wave] = sq; }
    __syncthreads();
    if (tid == 0) {
        s1[bc] = r1[0] + r1[1] + r1[2] + r1[3];
        s2[bc] = r2[0] + r2[1] + r2[2] + r2[3];
    }
}

// ---------------------------------------------------------------------------
// K4: per-batch LayerNorm stats from per-channel sums (up never materialized)
// ---------------------------------------------------------------------------
__global__ __launch_bounds__(256) void stats_k(const float* __restrict__ s1,
                                               const float* __restrict__ s2,
                                               const float* __restrict__ wlp,
                                               const float* __restrict__ blp,
                                               float* __restrict__ stats) {
    int b = blockIdx.x;
    int c = threadIdx.x;
    float w0 = wlp[c * 4], w1 = wlp[c * 4 + 1], w2 = wlp[c * 4 + 2], w3 = wlp[c * 4 + 3];
    float S1 = w0 + w1 + w2 + w3;
    float S2 = w0 * w0 + w1 * w1 + w2 * w2 + w3 * w3;
    float bl = blp[c];
    float cs = s1[b * 256 + c], cq = s2[b * 256 + c];
    float su = S1 * cs + 4096.f * bl;
    float sq = S2 * cq + 2.f * bl * S1 * cs + 4096.f * bl * bl;
    __shared__ float rs_[256], rq_[256];
    rs_[c] = su;
    rq_[c] = sq;
    __syncthreads();
    for (int o = 128; o > 0; o >>= 1) {
        if (c < o) { rs_[c] += rs_[c + o]; rq_[c] += rq_[c + o]; }
        __syncthreads();
    }
    if (c == 0) {
        const float N = 1048576.f;  // 256 * 64 * 64
        float mu = rs_[0] / N;
        float var = rq_[0] / N - mu * mu;
        stats[b] = mu;
        stats[8 + b] = rsqrtf(var + 1e-5f);
    }
}

// ---------------------------------------------------------------------------
// K5: projection GEMM with fused upsample + LayerNorm + affine.
// y[b,o,m'] = sum_c wp[o,c] * normed[c,m'],
// normed = A_c*wlp[c,p,q]*out[b,c,h,w] + (A_c*(blp[c]-mu) + beta[c]), A_c=gamma[c]*rs
// block: one h' row (64 w') x 64 o's.
// ---------------------------------------------------------------------------
__global__ __launch_bounds__(256) void proj_gemm_k(const float* __restrict__ ao,
                                                   const float* __restrict__ wp,
                                                   const float* __restrict__ wlp,
                                                   const float* __restrict__ blp,
                                                   const float* __restrict__ gamma,
                                                   const float* __restrict__ beta,
                                                   const float* __restrict__ stats,
                                                   float* __restrict__ y) {
    int b = blockIdx.z;
    int otile = blockIdx.y * 64;
    int hp = blockIdx.x;  // h' in [0,64)
    float mu = stats[b], rs = stats[8 + b];
    int pr = hp & 1, h = hp >> 1;
    __shared__ float As[32][65];
    __shared__ float Bs[32][65];
    float acc[4][4] = {};
    int tx = threadIdx.x & 15, ty = threadIdx.x >> 4;

    for (int kc = 0; kc < 256; kc += 32) {
        for (int idx = threadIdx.x; idx < 2048; idx += 256) {
            int kk = idx >> 6, oo = idx & 63;
            As[kk][oo] = wp[(size_t)(otile + oo) * 256 + kc + kk];
        }
        for (int idx = threadIdx.x; idx < 2048; idx += 256) {
            int kk = idx >> 6, nn = idx & 63;  // nn = w'
            int c = kc + kk;
            int q = nn & 1, w = nn >> 1;
            float ov = ao[((size_t)b * 256 + c) * 1024 + h * 32 + w];
            float A = gamma[c] * rs;
            Bs[kk][nn] = A * wlp[c * 4 + pr * 2 + q] * ov + (A * (blp[c] - mu) + beta[c]);
        }
        __syncthreads();
#pragma unroll
        for (int kk = 0; kk < 32; ++kk) {
            float a[4], bv[4];
#pragma unroll
            for (int i = 0; i < 4; ++i) a[i] = As[kk][ty * 4 + i];
#pragma unroll
            for (int j = 0; j < 4; ++j) bv[j] = Bs[kk][tx * 4 + j];
#pragma unroll
            for (int i = 0; i < 4; ++i)
#pragma unroll
                for (int j = 0; j < 4; ++j) acc[i][j] += a[i] * bv[j];
        }
        __syncthreads();
    }
#pragma unroll
    for (int i = 0; i < 4; ++i) {
        int o = otile + ty * 4 + i;
#pragma unroll
        for (int j = 0; j < 4; ++j)
            y[((size_t)b * 256 + o) * 4096 + hp * 64 + tx * 4 + j] = acc[i][j];
    }
}

extern "C" void kernel_launch(void* const* d_in, const int* in_sizes, int n_in,
                              void* d_out, int out_size, void* d_ws, size_t ws_size,
                              hipStream_t stream) {
    const float* x      = (const float*)d_in[0];
    const float* w_qkv  = (const float*)d_in[1];
    const float* w_lp   = (const float*)d_in[2];
    const float* b_lp   = (const float*)d_in[3];
    const float* gamma  = (const float*)d_in[4];
    const float* beta   = (const float*)d_in[5];
    const float* w_proj = (const float*)d_in[6];
    float* y = (float*)d_out;

    // d_out doubles as scratch for qkv (6.3M floats < 8.4M out elements);
    // proj overwrites it with y only after attn has consumed qkv.
    float* qkv = y;
    float* ws  = (float*)d_ws;
    float* ao    = ws;              // 8*256*1024 = 2097152 floats
    float* s1    = ao + 2097152;    // 2048
    float* s2    = s1 + 2048;       // 2048
    float* stats = s2 + 2048;       // 16

    qkv_gemm_k<<<dim3(16, 12, 8), 256, 0, stream>>>(x, w_qkv, qkv);
    attn_k<<<dim3(1024 / TI, 8, 8), 256, 0, stream>>>(qkv, ao);
    colsum_k<<<2048, 256, 0, stream>>>(ao, s1, s2);
    stats_k<<<8, 256, 0, stream>>>(s1, s2, w_lp, b_lp, stats);
    proj_gemm_k<<<dim3(64, 4, 8), 256, 0, stream>>>(ao, w_proj, w_lp, b_lp, gamma, beta, stats, y);
}

// Round 2
// 199.164 us; speedup vs baseline: 3.4425x; 3.4425x over previous
//
#include <hip/hip_runtime.h>
#include <hip/hip_bf16.h>

#define ATT_SCALE 0.17677669529663687f

typedef __attribute__((ext_vector_type(8))) short bf16x8;
typedef __attribute__((ext_vector_type(4))) float f32x4;

#define MFMA16(a, b, c) __builtin_amdgcn_mfma_f32_16x16x32_bf16(a, b, c, 0, 0, 0)

__device__ inline short f2b(float f) {
    return __builtin_bit_cast(short, __float2bfloat16(f));
}

// ---------------------------------------------------------------------------
// K1: fused downsample + QKV GEMM (fp32 compute), bf16 outputs in MFMA layouts:
//   qt[bh][n][d] (q * SCALE), kt[bh][n][d], v[bh][d][n]
// ---------------------------------------------------------------------------
__global__ __launch_bounds__(256) void qkv_gemm_k(const float* __restrict__ x,
                                                  const float* __restrict__ w,
                                                  short* __restrict__ qt,
                                                  short* __restrict__ kt,
                                                  short* __restrict__ vv) {
    int b = blockIdx.z;
    int otile = blockIdx.y * 64;
    int ntile = blockIdx.x * 64;
    __shared__ float As[32][65];
    __shared__ float Bs[32][65];
    float acc[4][4] = {};
    int tx = threadIdx.x & 15, ty = threadIdx.x >> 4;
    const float* xb = x + (size_t)b * 256 * 4096;

    for (int kc = 0; kc < 256; kc += 32) {
        for (int idx = threadIdx.x; idx < 2048; idx += 256) {
            int kk = idx >> 6, oo = idx & 63;
            As[kk][oo] = w[(size_t)(otile + oo) * 256 + kc + kk];
        }
        for (int idx = threadIdx.x; idx < 2048; idx += 256) {
            int kk = idx >> 6, nn = idx & 63;
            int n = ntile + nn;
            Bs[kk][nn] = xb[(size_t)(kc + kk) * 4096 + (n >> 5) * 128 + 2 * (n & 31)];
        }
        __syncthreads();
#pragma unroll
        for (int kk = 0; kk < 32; ++kk) {
            float a[4], bv[4];
#pragma unroll
            for (int i = 0; i < 4; ++i) a[i] = As[kk][ty * 4 + i];
#pragma unroll
            for (int j = 0; j < 4; ++j) bv[j] = Bs[kk][tx * 4 + j];
#pragma unroll
            for (int i = 0; i < 4; ++i)
#pragma unroll
                for (int j = 0; j < 4; ++j) acc[i][j] += a[i] * bv[j];
        }
        __syncthreads();
    }
#pragma unroll
    for (int i = 0; i < 4; ++i) {
        int o = otile + ty * 4 + i;
        int h = o / 96, r = o % 96;
        size_t bh = (size_t)b * 8 + h;
#pragma unroll
        for (int j = 0; j < 4; ++j) {
            int n = ntile + tx * 4 + j;
            float a = acc[i][j];
            if (r < 32)       qt[(bh * 1024 + n) * 32 + r] = f2b(a * ATT_SCALE);
            else if (r < 64)  kt[(bh * 1024 + n) * 32 + (r - 32)] = f2b(a);
            else              vv[(bh * 32 + (r - 64)) * 1024 + n] = f2b(a);
        }
    }
}

// ---------------------------------------------------------------------------
// K2: MFMA attention. Block = (itile of 128 rows, h, b); 4 waves, wave owns 32
// rows. No max-subtraction (scores bounded), no cross-wave sync.
// Output transposed: ao_t[b][n][c].
// ---------------------------------------------------------------------------
__global__ __launch_bounds__(256) void attn_k(const short* __restrict__ qt,
                                              const short* __restrict__ kt,
                                              const short* __restrict__ vv,
                                              float* __restrict__ ao_t) {
    int b = blockIdx.z, h = blockIdx.y;
    int bh = b * 8 + h;
    int w = threadIdx.x >> 6;
    int l = threadIdx.x & 63;
    int g = l >> 4, li = l & 15;
    int ibase = blockIdx.x * 128 + w * 32;

    __shared__ short Plds[4][16][136];  // per-wave, pitch 272B (17*16: aligned, spread banks)
    short (*P)[136] = Plds[w];

    const short* qtb = qt + (size_t)bh * 1024 * 32;
    const short* ktb = kt + (size_t)bh * 1024 * 32;
    const short* vb  = vv + (size_t)bh * 32 * 1024;

    bf16x8 aq[2];
#pragma unroll
    for (int ig = 0; ig < 2; ++ig)
        aq[ig] = *(const bf16x8*)(qtb + (size_t)(ibase + ig * 16 + li) * 32 + 8 * g);

    f32x4 zero = {0.f, 0.f, 0.f, 0.f};
    f32x4 of[2][2];
    float lrun[2][4];
#pragma unroll
    for (int ig = 0; ig < 2; ++ig) {
#pragma unroll
        for (int dg = 0; dg < 2; ++dg) of[ig][dg] = zero;
#pragma unroll
        for (int r = 0; r < 4; ++r) lrun[ig][r] = 0.f;
    }

    for (int j0 = 0; j0 < 1024; j0 += 128) {
        bf16x8 bk[8];
#pragma unroll
        for (int jt = 0; jt < 8; ++jt)
            bk[jt] = *(const bf16x8*)(ktb + (size_t)(j0 + jt * 16 + li) * 32 + 8 * g);
#pragma unroll
        for (int ig = 0; ig < 2; ++ig) {
            f32x4 s[8];
#pragma unroll
            for (int jt = 0; jt < 8; ++jt) s[jt] = MFMA16(aq[ig], bk[jt], zero);
            // exp (no max subtraction; scores bounded ~|6|)
#pragma unroll
            for (int jt = 0; jt < 8; ++jt)
#pragma unroll
                for (int r = 0; r < 4; ++r) s[jt][r] = __expf(s[jt][r]);
            // row sums -> lrun
#pragma unroll
            for (int r = 0; r < 4; ++r) {
                float t = 0.f;
#pragma unroll
                for (int jt = 0; jt < 8; ++jt) t += s[jt][r];
#pragma unroll
                for (int o = 1; o < 16; o <<= 1) t += __shfl_xor(t, o);
                lrun[ig][r] += t;
            }
            // P -> bf16 -> per-wave LDS (row = 4g+r, col = jt*16+li)
#pragma unroll
            for (int jt = 0; jt < 8; ++jt)
#pragma unroll
                for (int r = 0; r < 4; ++r)
                    P[4 * g + r][jt * 16 + li] = f2b(s[jt][r]);
            // PV: O[i][d] += P[i][j] * v[d][j]
#pragma unroll
            for (int ks = 0; ks < 4; ++ks) {
                bf16x8 ap = *(const bf16x8*)(&P[li][ks * 32 + 8 * g]);
#pragma unroll
                for (int dg = 0; dg < 2; ++dg) {
                    bf16x8 bv = *(const bf16x8*)(vb + (size_t)(dg * 16 + li) * 1024 + j0 + ks * 32 + 8 * g);
                    of[ig][dg] = MFMA16(ap, bv, of[ig][dg]);
                }
            }
        }
    }

#pragma unroll
    for (int ig = 0; ig < 2; ++ig)
#pragma unroll
        for (int r = 0; r < 4; ++r) {
            float inv = 1.f / lrun[ig][r];
            int n = ibase + ig * 16 + 4 * g + r;
#pragma unroll
            for (int dg = 0; dg < 2; ++dg)
                ao_t[((size_t)b * 1024 + n) * 256 + h * 32 + dg * 16 + li] = of[ig][dg][r] * inv;
        }
}

// ---------------------------------------------------------------------------
// K3: partial per-(b,c) sum/sumsq over 128-n chunks of ao_t
// ---------------------------------------------------------------------------
__global__ __launch_bounds__(256) void psum_k(const float* __restrict__ ao_t,
                                              float* __restrict__ p1,
                                              float* __restrict__ p2) {
    int nc = blockIdx.x, b = blockIdx.y, c = threadIdx.x;
    const float* base = ao_t + ((size_t)b * 1024 + nc * 128) * 256 + c;
    float s = 0.f, q = 0.f;
    for (int n = 0; n < 128; ++n) {
        float v = base[(size_t)n * 256];
        s += v; q += v * v;
    }
    int idx = (b * 8 + nc) * 256 + c;
    p1[idx] = s; p2[idx] = q;
}

// ---------------------------------------------------------------------------
// K4: per-batch LayerNorm stats (up never materialized)
// ---------------------------------------------------------------------------
__global__ __launch_bounds__(256) void stats_k(const float* __restrict__ p1,
                                               const float* __restrict__ p2,
                                               const float* __restrict__ wlp,
                                               const float* __restrict__ blp,
                                               float* __restrict__ stats) {
    int b = blockIdx.x, c = threadIdx.x;
    float s = 0.f, q = 0.f;
    for (int nc = 0; nc < 8; ++nc) {
        s += p1[(b * 8 + nc) * 256 + c];
        q += p2[(b * 8 + nc) * 256 + c];
    }
    float w0 = wlp[c * 4], w1 = wlp[c * 4 + 1], w2 = wlp[c * 4 + 2], w3 = wlp[c * 4 + 3];
    float S1 = w0 + w1 + w2 + w3, S2 = w0 * w0 + w1 * w1 + w2 * w2 + w3 * w3;
    float bl = blp[c];
    float su = S1 * s + 4096.f * bl;
    float sq = S2 * q + 2.f * bl * S1 * s + 4096.f * bl * bl;
    __shared__ float rs_[256], rq_[256];
    rs_[c] = su; rq_[c] = sq;
    __syncthreads();
    for (int o = 128; o > 0; o >>= 1) {
        if (c < o) { rs_[c] += rs_[c + o]; rq_[c] += rq_[c + o]; }
        __syncthreads();
    }
    if (c == 0) {
        const float N = 1048576.f;
        float mu = rs_[0] / N;
        float var = rq_[0] / N - mu * mu;
        stats[b] = mu;
        stats[8 + b] = rsqrtf(var + 1e-5f);
    }
}

// ---------------------------------------------------------------------------
// K5: MFMA projection GEMM with fused upsample+LayerNorm B-operand.
// Block: 64 o x 128 m (= 2 h' rows), K=256 in chunks of 32. 4 waves.
// ---------------------------------------------------------------------------
__global__ __launch_bounds__(256) void proj_k(const float* __restrict__ ao_t,
                                              const float* __restrict__ wp,
                                              const float* __restrict__ wlp,
                                              const float* __restrict__ blp,
                                              const float* __restrict__ gamma,
                                              const float* __restrict__ beta,
                                              const float* __restrict__ stats,
                                              float* __restrict__ y) {
    int b = blockIdx.z;
    int otile = blockIdx.y * 64;
    int mt = blockIdx.x;  // covers m = mt*128 .. +128 (h' rows 2mt, 2mt+1)
    float mu = stats[b], rs = stats[8 + b];

    __shared__ short As[64][40];   // pitch 80B: aligned + bank-spread
    __shared__ short Bs[128][40];

    int t = threadIdx.x;
    int w = t >> 6, l = t & 63, g = l >> 4, li = l & 15;
    int oh = (w >> 1) * 32, mh = (w & 1) * 64;

    f32x4 zero = {0.f, 0.f, 0.f, 0.f};
    f32x4 acc[2][4];
#pragma unroll
    for (int og = 0; og < 2; ++og)
#pragma unroll
        for (int mg = 0; mg < 4; ++mg) acc[og][mg] = zero;

    int so = t >> 2, sc = (t & 3) * 8;   // As roles: o = so, c = sc..sc+7
    int bc = t & 31, bm = (t >> 5) * 16; // Bs roles: c = bc, m = bm..bm+15
    int p = t >> 7;                      // = (m>>6) for this thread's m range
    int wbase = bm & 63;

    for (int kc = 0; kc < 256; kc += 32) {
        // stage A (w_proj -> bf16)
        const float* wrow = wp + (size_t)(otile + so) * 256 + kc + sc;
#pragma unroll
        for (int j = 0; j < 8; ++j) As[so][sc + j] = f2b(wrow[j]);
        // stage B (normed -> bf16), normed = Ac*wlp[c,p,q]*ao + Dc
        int c = kc + bc;
        float Ac = gamma[c] * rs;
        float Dc = Ac * (blp[c] - mu) + beta[c];
        float w0 = Ac * wlp[c * 4 + p * 2 + 0];
        float w1 = Ac * wlp[c * 4 + p * 2 + 1];
        const float* arow = ao_t + ((size_t)b * 1024 + mt * 32) * 256 + c;
#pragma unroll
        for (int k = 0; k < 8; ++k) {
            float av = arow[(size_t)(wbase / 2 + k) * 256];
            Bs[bm + 2 * k    ][bc] = f2b(w0 * av + Dc);
            Bs[bm + 2 * k + 1][bc] = f2b(w1 * av + Dc);
        }
        __syncthreads();
        bf16x8 af[2], bf_[4];
#pragma unroll
        for (int og = 0; og < 2; ++og) af[og] = *(const bf16x8*)&As[oh + og * 16 + li][8 * g];
#pragma unroll
        for (int mg = 0; mg < 4; ++mg) bf_[mg] = *(const bf16x8*)&Bs[mh + mg * 16 + li][8 * g];
#pragma unroll
        for (int og = 0; og < 2; ++og)
#pragma unroll
            for (int mg = 0; mg < 4; ++mg) acc[og][mg] = MFMA16(af[og], bf_[mg], acc[og][mg]);
        __syncthreads();
    }

#pragma unroll
    for (int og = 0; og < 2; ++og) {
        int o = otile + oh + og * 16 + 4 * g;
#pragma unroll
        for (int mg = 0; mg < 4; ++mg) {
            int m = mt * 128 + mh + mg * 16 + li;
            float* yp = y + ((size_t)b * 256 + o) * 4096 + m;
#pragma unroll
            for (int r = 0; r < 4; ++r) yp[(size_t)r * 4096] = acc[og][mg][r];
        }
    }
}

extern "C" void kernel_launch(void* const* d_in, const int* in_sizes, int n_in,
                              void* d_out, int out_size, void* d_ws, size_t ws_size,
                              hipStream_t stream) {
    const float* x      = (const float*)d_in[0];
    const float* w_qkv  = (const float*)d_in[1];
    const float* w_lp   = (const float*)d_in[2];
    const float* b_lp   = (const float*)d_in[3];
    const float* gamma  = (const float*)d_in[4];
    const float* beta   = (const float*)d_in[5];
    const float* w_proj = (const float*)d_in[6];
    float* y = (float*)d_out;

    // d_out (8.4M floats = 33.5MB) doubles as bf16 scratch for qt/kt/v (12MB);
    // proj overwrites it with y only after attention consumed them.
    short* qt = (short*)d_out;
    short* kt = qt + 2097152;
    short* vv = kt + 2097152;

    float* ao_t  = (float*)d_ws;          // 8*1024*256 = 2097152 floats
    float* p1    = ao_t + 2097152;        // 64*256
    float* p2    = p1 + 16384;            // 64*256
    float* stats = p2 + 16384;            // 16

    qkv_gemm_k<<<dim3(16, 12, 8), 256, 0, stream>>>(x, w_qkv, qt, kt, vv);
    attn_k<<<dim3(8, 8, 8), 256, 0, stream>>>(qt, kt, vv, ao_t);
    psum_k<<<dim3(8, 8), 256, 0, stream>>>(ao_t, p1, p2);
    stats_k<<<8, 256, 0, stream>>>(p1, p2, w_lp, b_lp, stats);
    proj_k<<<dim3(32, 4, 8), 256, 0, stream>>>(ao_t, w_proj, w_lp, b_lp, gamma, beta, stats, y);
}

// Round 3
// 106.422 us; speedup vs baseline: 6.4426x; 1.8715x over previous
//
#include <hip/hip_runtime.h>
#include <hip/hip_bf16.h>

#define ATT_SCALE 0.17677669529663687f

typedef __attribute__((ext_vector_type(8))) short bf16x8;
typedef __attribute__((ext_vector_type(4))) float f32x4;

#define MFMA16(a, b, c) __builtin_amdgcn_mfma_f32_16x16x32_bf16(a, b, c, 0, 0, 0)

__device__ inline short f2b(float f) {
    return __builtin_bit_cast(short, __float2bfloat16(f));
}

// ---------------------------------------------------------------------------
// K0a: w_qkv fp32 -> bf16
// ---------------------------------------------------------------------------
__global__ __launch_bounds__(256) void wconv_k(const float* __restrict__ w,
                                               short* __restrict__ wb) {
    int i0 = (blockIdx.x * 256 + threadIdx.x) * 8;
    float4 lo = *(const float4*)(w + i0);
    float4 hi = *(const float4*)(w + i0 + 4);
    bf16x8 o;
    o[0] = f2b(lo.x); o[1] = f2b(lo.y); o[2] = f2b(lo.z); o[3] = f2b(lo.w);
    o[4] = f2b(hi.x); o[5] = f2b(hi.y); o[6] = f2b(hi.z); o[7] = f2b(hi.w);
    *(bf16x8*)(wb + i0) = o;
}

// ---------------------------------------------------------------------------
// K0b: fused downsample + transpose + bf16: xt[b][n][c], n = h*32+w over
// x[b][c][2h][2w]. Gather reads (L2/HBM), coalesced 16B writes.
// ---------------------------------------------------------------------------
__global__ __launch_bounds__(256) void xt_k(const float* __restrict__ x,
                                            short* __restrict__ xt) {
    int b = blockIdx.y;
    int t = threadIdx.x;
    int n = blockIdx.x * 32 + (t >> 3);
    const float* xb = x + (size_t)b * 1048576 + (n >> 5) * 128 + (n & 31) * 2;
    short* dst = xt + ((size_t)b * 1024 + n) * 256;
#pragma unroll
    for (int it = 0; it < 4; ++it) {
        int c = (t & 7) * 8 + it * 64;
        bf16x8 o;
#pragma unroll
        for (int j = 0; j < 8; ++j) o[j] = f2b(xb[(size_t)(c + j) * 4096]);
        *(bf16x8*)(dst + c) = o;
    }
}

// ---------------------------------------------------------------------------
// K1: QKV MFMA GEMM, no LDS in main loop. Block = 64 o x 128 n, 4 waves
// (wave = 32 o x 64 n). Each 32-o group is exactly one of q/k/v of one head.
// Epilogue: per-wave XOR-swizzled LDS transpose -> vectorized stores into
//   qt[bh][n][32] (q * SCALE), kt[bh][n][32], vv[bh][32][n].
// ---------------------------------------------------------------------------
__global__ __launch_bounds__(256) void qkv_k(const short* __restrict__ wb,
                                             const short* __restrict__ xt,
                                             short* __restrict__ qt,
                                             short* __restrict__ kt,
                                             short* __restrict__ vv) {
    int b = blockIdx.z;
    int otile = blockIdx.y * 64;
    int ntile = blockIdx.x * 128;
    int t = threadIdx.x;
    int w = t >> 6, l = t & 63, g = l >> 4, li = l & 15;
    int oh = (w & 1) * 32, mh = (w >> 1) * 64;
    int o_base = otile + oh;
    int head = o_base / 96;
    int role = (o_base >> 5) % 3;  // 0=q 1=k 2=v
    size_t bh = (size_t)b * 8 + head;

    const short* arow = wb + (size_t)o_base * 256;
    const short* brow = xt + ((size_t)b * 1024 + ntile + mh) * 256;

    f32x4 zero = {0.f, 0.f, 0.f, 0.f};
    f32x4 acc[2][4];
#pragma unroll
    for (int og = 0; og < 2; ++og)
#pragma unroll
        for (int mg = 0; mg < 4; ++mg) acc[og][mg] = zero;

#pragma unroll
    for (int kc = 0; kc < 256; kc += 32) {
        bf16x8 af[2], bf_[4];
#pragma unroll
        for (int og = 0; og < 2; ++og)
            af[og] = *(const bf16x8*)(arow + (size_t)(og * 16 + li) * 256 + kc + 8 * g);
#pragma unroll
        for (int mg = 0; mg < 4; ++mg)
            bf_[mg] = *(const bf16x8*)(brow + (size_t)(mg * 16 + li) * 256 + kc + 8 * g);
#pragma unroll
        for (int og = 0; og < 2; ++og)
#pragma unroll
            for (int mg = 0; mg < 4; ++mg)
                acc[og][mg] = MFMA16(af[og], bf_[mg], acc[og][mg]);
    }

    // ---- epilogue: per-wave LDS transpose tile T[32 o'][64 n'], columns
    // XOR-swizzled by bits 4-5 with (o'>>3)&3 for conflict-free access.
    __shared__ short Tl[4][32][64];
    short (*Tw)[64] = Tl[w];
    float sc = (role == 0) ? ATT_SCALE : 1.f;

#pragma unroll
    for (int og = 0; og < 2; ++og)
#pragma unroll
        for (int mg = 0; mg < 4; ++mg)
#pragma unroll
            for (int r = 0; r < 4; ++r) {
                int op = og * 16 + 4 * g + r;
                int qp = (op >> 3) & 3;
                Tw[op][(mg * 16 + li) ^ (qp << 4)] = f2b(acc[og][mg][r] * sc);
            }
    __syncthreads();

    if (role == 2) {
        // v: want vv[bh*32 + d][n] — row-major 16B chunks
#pragma unroll
        for (int it = 0; it < 4; ++it) {
            int s = it * 64 + l;
            int o2 = s >> 3;           // d 0..31
            int n8 = (s & 7) * 8;      // n' chunk
            int q2 = (o2 >> 3) & 3;
            bf16x8 vo = *(const bf16x8*)&Tw[o2][n8 ^ (q2 << 4)];
            *(bf16x8*)(vv + ((size_t)bh * 32 + o2) * 1024 + ntile + mh + n8) = vo;
        }
    } else {
        short* dst = (role == 0) ? qt : kt;
        // q/k: want dst[bh*1024 + n][d] — gather 8 d's per n
#pragma unroll
        for (int it = 0; it < 4; ++it) {
            int s = it * 64 + l;
            int dq = (l & 3) * 8;      // d-octet
            int n = s >> 2;            // n' 0..63
            int q2 = dq >> 3;          // = (dq+j)>>3 & 3 for j<8
            bf16x8 vo;
#pragma unroll
            for (int j = 0; j < 8; ++j)
                vo[j] = Tw[dq + j][n ^ (q2 << 4)];
            *(bf16x8*)(dst + ((size_t)bh * 1024 + ntile + mh + n) * 32 + dq) = vo;
        }
    }
}

// ---------------------------------------------------------------------------
// K2: MFMA attention (unchanged). Block = (itile 128, h, b); 4 waves.
// Output transposed: ao_t[b][n][c].
// ---------------------------------------------------------------------------
__global__ __launch_bounds__(256) void attn_k(const short* __restrict__ qt,
                                              const short* __restrict__ kt,
                                              const short* __restrict__ vv,
                                              float* __restrict__ ao_t) {
    int b = blockIdx.z, h = blockIdx.y;
    int bh = b * 8 + h;
    int w = threadIdx.x >> 6;
    int l = threadIdx.x & 63;
    int g = l >> 4, li = l & 15;
    int ibase = blockIdx.x * 128 + w * 32;

    __shared__ short Plds[4][16][136];
    short (*P)[136] = Plds[w];

    const short* qtb = qt + (size_t)bh * 1024 * 32;
    const short* ktb = kt + (size_t)bh * 1024 * 32;
    const short* vb  = vv + (size_t)bh * 32 * 1024;

    bf16x8 aq[2];
#pragma unroll
    for (int ig = 0; ig < 2; ++ig)
        aq[ig] = *(const bf16x8*)(qtb + (size_t)(ibase + ig * 16 + li) * 32 + 8 * g);

    f32x4 zero = {0.f, 0.f, 0.f, 0.f};
    f32x4 of[2][2];
    float lrun[2][4];
#pragma unroll
    for (int ig = 0; ig < 2; ++ig) {
#pragma unroll
        for (int dg = 0; dg < 2; ++dg) of[ig][dg] = zero;
#pragma unroll
        for (int r = 0; r < 4; ++r) lrun[ig][r] = 0.f;
    }

    for (int j0 = 0; j0 < 1024; j0 += 128) {
        bf16x8 bk[8];
#pragma unroll
        for (int jt = 0; jt < 8; ++jt)
            bk[jt] = *(const bf16x8*)(ktb + (size_t)(j0 + jt * 16 + li) * 32 + 8 * g);
#pragma unroll
        for (int ig = 0; ig < 2; ++ig) {
            f32x4 s[8];
#pragma unroll
            for (int jt = 0; jt < 8; ++jt) s[jt] = MFMA16(aq[ig], bk[jt], zero);
#pragma unroll
            for (int jt = 0; jt < 8; ++jt)
#pragma unroll
                for (int r = 0; r < 4; ++r) s[jt][r] = __expf(s[jt][r]);
#pragma unroll
            for (int r = 0; r < 4; ++r) {
                float tt = 0.f;
#pragma unroll
                for (int jt = 0; jt < 8; ++jt) tt += s[jt][r];
#pragma unroll
                for (int o = 1; o < 16; o <<= 1) tt += __shfl_xor(tt, o);
                lrun[ig][r] += tt;
            }
#pragma unroll
            for (int jt = 0; jt < 8; ++jt)
#pragma unroll
                for (int r = 0; r < 4; ++r)
                    P[4 * g + r][jt * 16 + li] = f2b(s[jt][r]);
#pragma unroll
            for (int ks = 0; ks < 4; ++ks) {
                bf16x8 ap = *(const bf16x8*)(&P[li][ks * 32 + 8 * g]);
#pragma unroll
                for (int dg = 0; dg < 2; ++dg) {
                    bf16x8 bv = *(const bf16x8*)(vb + (size_t)(dg * 16 + li) * 1024 + j0 + ks * 32 + 8 * g);
                    of[ig][dg] = MFMA16(ap, bv, of[ig][dg]);
                }
            }
        }
    }

#pragma unroll
    for (int ig = 0; ig < 2; ++ig)
#pragma unroll
        for (int r = 0; r < 4; ++r) {
            float inv = 1.f / lrun[ig][r];
            int n = ibase + ig * 16 + 4 * g + r;
#pragma unroll
            for (int dg = 0; dg < 2; ++dg)
                ao_t[((size_t)b * 1024 + n) * 256 + h * 32 + dg * 16 + li] = of[ig][dg][r] * inv;
        }
}

// ---------------------------------------------------------------------------
// K3: partial per-(b,c) sum/sumsq over 128-n chunks of ao_t
// ---------------------------------------------------------------------------
__global__ __launch_bounds__(256) void psum_k(const float* __restrict__ ao_t,
                                              float* __restrict__ p1,
                                              float* __restrict__ p2) {
    int nc = blockIdx.x, b = blockIdx.y, c = threadIdx.x;
    const float* base = ao_t + ((size_t)b * 1024 + nc * 128) * 256 + c;
    float s = 0.f, q = 0.f;
    for (int n = 0; n < 128; ++n) {
        float v = base[(size_t)n * 256];
        s += v; q += v * v;
    }
    int idx = (b * 8 + nc) * 256 + c;
    p1[idx] = s; p2[idx] = q;
}

// ---------------------------------------------------------------------------
// K4: per-batch LayerNorm stats (up never materialized)
// ---------------------------------------------------------------------------
__global__ __launch_bounds__(256) void stats_k(const float* __restrict__ p1,
                                               const float* __restrict__ p2,
                                               const float* __restrict__ wlp,
                                               const float* __restrict__ blp,
                                               float* __restrict__ stats) {
    int b = blockIdx.x, c = threadIdx.x;
    float s = 0.f, q = 0.f;
    for (int nc = 0; nc < 8; ++nc) {
        s += p1[(b * 8 + nc) * 256 + c];
        q += p2[(b * 8 + nc) * 256 + c];
    }
    float w0 = wlp[c * 4], w1 = wlp[c * 4 + 1], w2 = wlp[c * 4 + 2], w3 = wlp[c * 4 + 3];
    float S1 = w0 + w1 + w2 + w3, S2 = w0 * w0 + w1 * w1 + w2 * w2 + w3 * w3;
    float bl = blp[c];
    float su = S1 * s + 4096.f * bl;
    float sq = S2 * q + 2.f * bl * S1 * s + 4096.f * bl * bl;
    __shared__ float rs_[256], rq_[256];
    rs_[c] = su; rq_[c] = sq;
    __syncthreads();
    for (int o = 128; o > 0; o >>= 1) {
        if (c < o) { rs_[c] += rs_[c + o]; rq_[c] += rq_[c + o]; }
        __syncthreads();
    }
    if (c == 0) {
        const float N = 1048576.f;
        float mu = rs_[0] / N;
        float var = rq_[0] / N - mu * mu;
        stats[b] = mu;
        stats[8 + b] = rsqrtf(var + 1e-5f);
    }
}

// ---------------------------------------------------------------------------
// K5: MFMA projection GEMM with fused upsample+LayerNorm B-operand.
// ---------------------------------------------------------------------------
__global__ __launch_bounds__(256) void proj_k(const float* __restrict__ ao_t,
                                              const float* __restrict__ wp,
                                              const float* __restrict__ wlp,
                                              const float* __restrict__ blp,
                                              const float* __restrict__ gamma,
                                              const float* __restrict__ beta,
                                              const float* __restrict__ stats,
                                              float* __restrict__ y) {
    int b = blockIdx.z;
    int otile = blockIdx.y * 64;
    int mt = blockIdx.x;
    float mu = stats[b], rs = stats[8 + b];

    __shared__ short As[64][40];
    __shared__ short Bs[128][40];

    int t = threadIdx.x;
    int w = t >> 6, l = t & 63, g = l >> 4, li = l & 15;
    int oh = (w >> 1) * 32, mh = (w & 1) * 64;

    f32x4 zero = {0.f, 0.f, 0.f, 0.f};
    f32x4 acc[2][4];
#pragma unroll
    for (int og = 0; og < 2; ++og)
#pragma unroll
        for (int mg = 0; mg < 4; ++mg) acc[og][mg] = zero;

    int so = t >> 2, sc = (t & 3) * 8;
    int bc = t & 31, bm = (t >> 5) * 16;
    int p = t >> 7;
    int wbase = bm & 63;

    for (int kc = 0; kc < 256; kc += 32) {
        const float* wrow = wp + (size_t)(otile + so) * 256 + kc + sc;
#pragma unroll
        for (int j = 0; j < 8; ++j) As[so][sc + j] = f2b(wrow[j]);
        int c = kc + bc;
        float Ac = gamma[c] * rs;
        float Dc = Ac * (blp[c] - mu) + beta[c];
        float w0 = Ac * wlp[c * 4 + p * 2 + 0];
        float w1 = Ac * wlp[c * 4 + p * 2 + 1];
        const float* arow = ao_t + ((size_t)b * 1024 + mt * 32) * 256 + c;
#pragma unroll
        for (int k = 0; k < 8; ++k) {
            float av = arow[(size_t)(wbase / 2 + k) * 256];
            Bs[bm + 2 * k    ][bc] = f2b(w0 * av + Dc);
            Bs[bm + 2 * k + 1][bc] = f2b(w1 * av + Dc);
        }
        __syncthreads();
        bf16x8 af[2], bf_[4];
#pragma unroll
        for (int og = 0; og < 2; ++og) af[og] = *(const bf16x8*)&As[oh + og * 16 + li][8 * g];
#pragma unroll
        for (int mg = 0; mg < 4; ++mg) bf_[mg] = *(const bf16x8*)&Bs[mh + mg * 16 + li][8 * g];
#pragma unroll
        for (int og = 0; og < 2; ++og)
#pragma unroll
            for (int mg = 0; mg < 4; ++mg) acc[og][mg] = MFMA16(af[og], bf_[mg], acc[og][mg]);
        __syncthreads();
    }

#pragma unroll
    for (int og = 0; og < 2; ++og) {
        int o = otile + oh + og * 16 + 4 * g;
#pragma unroll
        for (int mg = 0; mg < 4; ++mg) {
            int m = mt * 128 + mh + mg * 16 + li;
            float* yp = y + ((size_t)b * 256 + o) * 4096 + m;
#pragma unroll
            for (int r = 0; r < 4; ++r) yp[(size_t)r * 4096] = acc[og][mg][r];
        }
    }
}

extern "C" void kernel_launch(void* const* d_in, const int* in_sizes, int n_in,
                              void* d_out, int out_size, void* d_ws, size_t ws_size,
                              hipStream_t stream) {
    const float* x      = (const float*)d_in[0];
    const float* w_qkv  = (const float*)d_in[1];
    const float* w_lp   = (const float*)d_in[2];
    const float* b_lp   = (const float*)d_in[3];
    const float* gamma  = (const float*)d_in[4];
    const float* beta   = (const float*)d_in[5];
    const float* w_proj = (const float*)d_in[6];
    float* y = (float*)d_out;

    // d_out (16.7M shorts) doubles as bf16 scratch; proj overwrites with y
    // only after all consumers are done (stream-ordered).
    short* qt = (short*)d_out;          // 2097152 shorts
    short* kt = qt + 2097152;           // 2097152
    short* vv = kt + 2097152;           // 2097152
    short* xt = vv + 2097152;           // 2097152
    short* wbuf = xt + 2097152;         // 196608

    float* ao_t  = (float*)d_ws;        // 2097152 floats
    float* p1    = ao_t + 2097152;      // 16384
    float* p2    = p1 + 16384;          // 16384
    float* stats = p2 + 16384;          // 16

    wconv_k<<<96, 256, 0, stream>>>(w_qkv, wbuf);
    xt_k<<<dim3(32, 8), 256, 0, stream>>>(x, xt);
    qkv_k<<<dim3(8, 12, 8), 256, 0, stream>>>(wbuf, xt, qt, kt, vv);
    attn_k<<<dim3(8, 8, 8), 256, 0, stream>>>(qt, kt, vv, ao_t);
    psum_k<<<dim3(8, 8), 256, 0, stream>>>(ao_t, p1, p2);
    stats_k<<<8, 256, 0, stream>>>(p1, p2, w_lp, b_lp, stats);
    proj_k<<<dim3(32, 4, 8), 256, 0, stream>>>(ao_t, w_proj, w_lp, b_lp, gamma, beta, stats, y);
}

// Round 5
// 99.305 us; speedup vs baseline: 6.9043x; 1.0717x over previous
//
#include <hip/hip_runtime.h>
#include <hip/hip_bf16.h>

#define ATT_SCALE 0.17677669529663687f

typedef __attribute__((ext_vector_type(8))) short bf16x8;
typedef __attribute__((ext_vector_type(4))) short bf16x4;
typedef __attribute__((ext_vector_type(4))) float f32x4;
typedef __attribute__((ext_vector_type(16))) float f32x16;
typedef __attribute__((ext_vector_type(4))) int i32x4;

#define MFMA16(a, b, c) __builtin_amdgcn_mfma_f32_16x16x32_bf16(a, b, c, 0, 0, 0)
#define MFMA32(a, b, c) __builtin_amdgcn_mfma_f32_32x32x16_bf16(a, b, c, 0, 0, 0)

__device__ inline short f2b(float f) {
    return __builtin_bit_cast(short, __float2bfloat16(f));
}

__device__ inline int packbf(float a, float b) {
    unsigned lo = (unsigned short)f2b(a);
    unsigned hi = (unsigned short)f2b(b);
    return (int)(lo | (hi << 16));
}

__device__ inline bf16x8 cat4(bf16x4 a, bf16x4 b) {
    bf16x8 r;
    r[0] = a[0]; r[1] = a[1]; r[2] = a[2]; r[3] = a[3];
    r[4] = b[0]; r[5] = b[1]; r[6] = b[2]; r[7] = b[3];
    return r;
}

// ---------------------------------------------------------------------------
// K0a: w_qkv fp32 -> bf16
// ---------------------------------------------------------------------------
__global__ __launch_bounds__(256) void wconv_k(const float* __restrict__ w,
                                               short* __restrict__ wb) {
    int i0 = (blockIdx.x * 256 + threadIdx.x) * 8;
    float4 lo = *(const float4*)(w + i0);
    float4 hi = *(const float4*)(w + i0 + 4);
    bf16x8 o;
    o[0] = f2b(lo.x); o[1] = f2b(lo.y); o[2] = f2b(lo.z); o[3] = f2b(lo.w);
    o[4] = f2b(hi.x); o[5] = f2b(hi.y); o[6] = f2b(hi.z); o[7] = f2b(hi.w);
    *(bf16x8*)(wb + i0) = o;
}

// ---------------------------------------------------------------------------
// K0b: fused downsample + transpose + bf16: xt[b][n][c]
// ---------------------------------------------------------------------------
__global__ __launch_bounds__(256) void xt_k(const float* __restrict__ x,
                                            short* __restrict__ xt) {
    int b = blockIdx.y;
    int t = threadIdx.x;
    int n = blockIdx.x * 32 + (t >> 3);
    const float* xb = x + (size_t)b * 1048576 + (n >> 5) * 128 + (n & 31) * 2;
    short* dst = xt + ((size_t)b * 1024 + n) * 256;
#pragma unroll
    for (int it = 0; it < 4; ++it) {
        int c = (t & 7) * 8 + it * 64;
        bf16x8 o;
#pragma unroll
        for (int j = 0; j < 8; ++j) o[j] = f2b(xb[(size_t)(c + j) * 4096]);
        *(bf16x8*)(dst + c) = o;
    }
}

// ---------------------------------------------------------------------------
// K1: QKV MFMA GEMM (LDS-free main loop), epilogue transpose -> qt/kt/vv.
// ---------------------------------------------------------------------------
__global__ __launch_bounds__(256) void qkv_k(const short* __restrict__ wb,
                                             const short* __restrict__ xt,
                                             short* __restrict__ qt,
                                             short* __restrict__ kt,
                                             short* __restrict__ vv) {
    int b = blockIdx.z;
    int otile = blockIdx.y * 64;
    int ntile = blockIdx.x * 128;
    int t = threadIdx.x;
    int w = t >> 6, l = t & 63, g = l >> 4, li = l & 15;
    int oh = (w & 1) * 32, mh = (w >> 1) * 64;
    int o_base = otile + oh;
    int head = o_base / 96;
    int role = (o_base >> 5) % 3;  // 0=q 1=k 2=v
    size_t bh = (size_t)b * 8 + head;

    const short* arow = wb + (size_t)o_base * 256;
    const short* brow = xt + ((size_t)b * 1024 + ntile + mh) * 256;

    f32x4 zero = {0.f, 0.f, 0.f, 0.f};
    f32x4 acc[2][4];
#pragma unroll
    for (int og = 0; og < 2; ++og)
#pragma unroll
        for (int mg = 0; mg < 4; ++mg) acc[og][mg] = zero;

#pragma unroll
    for (int kc = 0; kc < 256; kc += 32) {
        bf16x8 af[2], bf_[4];
#pragma unroll
        for (int og = 0; og < 2; ++og)
            af[og] = *(const bf16x8*)(arow + (size_t)(og * 16 + li) * 256 + kc + 8 * g);
#pragma unroll
        for (int mg = 0; mg < 4; ++mg)
            bf_[mg] = *(const bf16x8*)(brow + (size_t)(mg * 16 + li) * 256 + kc + 8 * g);
#pragma unroll
        for (int og = 0; og < 2; ++og)
#pragma unroll
            for (int mg = 0; mg < 4; ++mg)
                acc[og][mg] = MFMA16(af[og], bf_[mg], acc[og][mg]);
    }

    __shared__ short Tl[4][32][64];
    short (*Tw)[64] = Tl[w];
    float sc = (role == 0) ? ATT_SCALE : 1.f;

#pragma unroll
    for (int og = 0; og < 2; ++og)
#pragma unroll
        for (int mg = 0; mg < 4; ++mg)
#pragma unroll
            for (int r = 0; r < 4; ++r) {
                int op = og * 16 + 4 * g + r;
                int qp = (op >> 3) & 3;
                Tw[op][(mg * 16 + li) ^ (qp << 4)] = f2b(acc[og][mg][r] * sc);
            }
    __syncthreads();

    if (role == 2) {
#pragma unroll
        for (int it = 0; it < 4; ++it) {
            int s = it * 64 + l;
            int o2 = s >> 3;
            int n8 = (s & 7) * 8;
            int q2 = (o2 >> 3) & 3;
            bf16x8 vo = *(const bf16x8*)&Tw[o2][n8 ^ (q2 << 4)];
            *(bf16x8*)(vv + ((size_t)bh * 32 + o2) * 1024 + ntile + mh + n8) = vo;
        }
    } else {
        short* dst = (role == 0) ? qt : kt;
#pragma unroll
        for (int it = 0; it < 4; ++it) {
            int s = it * 64 + l;
            int dq = (l & 3) * 8;
            int n = s >> 2;
            int q2 = dq >> 3;
            bf16x8 vo;
#pragma unroll
            for (int j = 0; j < 8; ++j)
                vo[j] = Tw[dq + j][n ^ (q2 << 4)];
            *(bf16x8*)(dst + ((size_t)bh * 1024 + ntile + mh + n) * 32 + dq) = vo;
        }
    }
}

// ---------------------------------------------------------------------------
// K2: attention, swapped-QK^T 32x32 MFMA, P fully lane-local (no LDS, no
// cross-lane P exchange). Lane (il,hi) holds p[r] = P[j0+rho(r,hi)][il] with
// rho(r,hi) = (r&3)+8*(r>>2)+4*hi (HW-verified C/D map). PV uses the SAME
// slot map on both operands: P-frag = pack(p[0..7]) / pack(p[8..15]); V is
// loaded at matching n = j0 + rho(...) via split 8B loads -> exact by
// permutation-invariance of the MFMA contraction.
// Output ao2[b][c][n] (c = h*32+d).
// ---------------------------------------------------------------------------
__global__ __launch_bounds__(256) void attn_k(const short* __restrict__ qt,
                                              const short* __restrict__ kt,
                                              const short* __restrict__ vv,
                                              float* __restrict__ ao2) {
    int b = blockIdx.z, h = blockIdx.y;
    int bh = b * 8 + h;
    int w = threadIdx.x >> 6, l = threadIdx.x & 63;
    int il = l & 31, hi = l >> 5;
    int ibase = blockIdx.x * 128 + w * 32;

    const short* qtb = qt + (size_t)bh * 32768;
    const short* ktb = kt + (size_t)bh * 32768;
    const short* vb  = vv + (size_t)bh * 32768;

    bf16x8 qf0 = *(const bf16x8*)(qtb + (size_t)(ibase + il) * 32 + 8 * hi);
    bf16x8 qf1 = *(const bf16x8*)(qtb + (size_t)(ibase + il) * 32 + 16 + 8 * hi);

    f32x16 zero16 = {0.f,0.f,0.f,0.f,0.f,0.f,0.f,0.f,0.f,0.f,0.f,0.f,0.f,0.f,0.f,0.f};
    f32x16 oacc = zero16;
    float lrun = 0.f;

#pragma unroll 2
    for (int j0 = 0; j0 < 1024; j0 += 32) {
        bf16x8 kf0 = *(const bf16x8*)(ktb + (size_t)(j0 + il) * 32 + 8 * hi);
        bf16x8 kf1 = *(const bf16x8*)(ktb + (size_t)(j0 + il) * 32 + 16 + 8 * hi);
        f32x16 s = MFMA32(kf0, qf0, zero16);
        s = MFMA32(kf1, qf1, s);

        float p[16];
#pragma unroll
        for (int r = 0; r < 16; ++r) {
            p[r] = __expf(s[r]);
            lrun += p[r];
        }

        // P fragments: element j of pfa = p[j] (rows j0 + rho(j,hi));
        //              element j of pfb = p[8+j] (rows j0 + 16 + rho(j,hi)).
        i32x4 fa, fb;
        fa[0] = packbf(p[0], p[1]);   fa[1] = packbf(p[2], p[3]);
        fa[2] = packbf(p[4], p[5]);   fa[3] = packbf(p[6], p[7]);
        fb[0] = packbf(p[8], p[9]);   fb[1] = packbf(p[10], p[11]);
        fb[2] = packbf(p[12], p[13]); fb[3] = packbf(p[14], p[15]);
        bf16x8 pfa = __builtin_bit_cast(bf16x8, fa);
        bf16x8 pfb = __builtin_bit_cast(bf16x8, fb);

        // V fragments with the same slot map: rho(j,hi) = (j&3)+8*(j>>2)+4hi
        // elems 0-3: n = j0+4hi+0..3 ; elems 4-7: n = j0+8+4hi+0..3 (+16 for b)
        const short* vrow = vb + (size_t)il * 1024 + j0 + 4 * hi;
        bf16x8 vfa = cat4(*(const bf16x4*)(vrow),      *(const bf16x4*)(vrow + 8));
        bf16x8 vfb = cat4(*(const bf16x4*)(vrow + 16), *(const bf16x4*)(vrow + 24));

        oacc = MFMA32(vfa, pfa, oacc);
        oacc = MFMA32(vfb, pfb, oacc);
    }

    float tot = lrun + __shfl_xor(lrun, 32);
    float inv = 1.f / tot;

    float* base = ao2 + ((size_t)(b * 256 + h * 32)) * 1024 + ibase + il;
#pragma unroll
    for (int r = 0; r < 16; ++r) {
        int d = (r & 3) + 8 * (r >> 2) + 4 * hi;
        base[(size_t)d * 1024] = oacc[r] * inv;
    }
}

// ---------------------------------------------------------------------------
// K3: per-(b,c) sum/sumsq of ao2 rows (contiguous 1024 floats). 1 wave/row.
// ---------------------------------------------------------------------------
__global__ __launch_bounds__(64) void psum_k(const float* __restrict__ ao2,
                                             float* __restrict__ p1,
                                             float* __restrict__ p2) {
    int row = blockIdx.x;
    const float* base = ao2 + (size_t)row * 1024;
    int l = threadIdx.x;
    float s = 0.f, q = 0.f;
#pragma unroll
    for (int t = 0; t < 4; ++t) {
        float4 v = *(const float4*)(base + l * 4 + t * 256);
        s += v.x + v.y + v.z + v.w;
        q += v.x * v.x + v.y * v.y + v.z * v.z + v.w * v.w;
    }
#pragma unroll
    for (int o = 1; o < 64; o <<= 1) {
        s += __shfl_xor(s, o);
        q += __shfl_xor(q, o);
    }
    if (l == 0) { p1[row] = s; p2[row] = q; }
}

// ---------------------------------------------------------------------------
// K4: per-batch LayerNorm stats (up never materialized)
// ---------------------------------------------------------------------------
__global__ __launch_bounds__(256) void stats_k(const float* __restrict__ p1,
                                               const float* __restrict__ p2,
                                               const float* __restrict__ wlp,
                                               const float* __restrict__ blp,
                                               float* __restrict__ stats) {
    int b = blockIdx.x, c = threadIdx.x;
    float s = p1[b * 256 + c];
    float q = p2[b * 256 + c];
    float w0 = wlp[c * 4], w1 = wlp[c * 4 + 1], w2 = wlp[c * 4 + 2], w3 = wlp[c * 4 + 3];
    float S1 = w0 + w1 + w2 + w3, S2 = w0 * w0 + w1 * w1 + w2 * w2 + w3 * w3;
    float bl = blp[c];
    float su = S1 * s + 4096.f * bl;
    float sq = S2 * q + 2.f * bl * S1 * s + 4096.f * bl * bl;
    __shared__ float rs_[256], rq_[256];
    rs_[c] = su; rq_[c] = sq;
    __syncthreads();
    for (int o = 128; o > 0; o >>= 1) {
        if (c < o) { rs_[c] += rs_[c + o]; rq_[c] += rq_[c + o]; }
        __syncthreads();
    }
    if (c == 0) {
        const float N = 1048576.f;
        float mu = rs_[0] / N;
        float var = rq_[0] / N - mu * mu;
        stats[b] = mu;
        stats[8 + b] = rsqrtf(var + 1e-5f);
    }
}

// ---------------------------------------------------------------------------
// K5: MFMA projection GEMM with fused upsample+LayerNorm B-operand.
// ao2 layout [b][c][n]: B-staging reads 32B contiguous per thread.
// ---------------------------------------------------------------------------
__global__ __launch_bounds__(256) void proj_k(const float* __restrict__ ao2,
                                              const float* __restrict__ wp,
                                              const float* __restrict__ wlp,
                                              const float* __restrict__ blp,
                                              const float* __restrict__ gamma,
                                              const float* __restrict__ beta,
                                              const float* __restrict__ stats,
                                              float* __restrict__ y) {
    int b = blockIdx.z;
    int otile = blockIdx.y * 64;
    int mt = blockIdx.x;
    float mu = stats[b], rs = stats[8 + b];

    __shared__ short As[64][40];
    __shared__ short Bs[128][40];

    int t = threadIdx.x;
    int w = t >> 6, l = t & 63, g = l >> 4, li = l & 15;
    int oh = (w >> 1) * 32, mh = (w & 1) * 64;

    f32x4 zero = {0.f, 0.f, 0.f, 0.f};
    f32x4 acc[2][4];
#pragma unroll
    for (int og = 0; og < 2; ++og)
#pragma unroll
        for (int mg = 0; mg < 4; ++mg) acc[og][mg] = zero;

    int so = t >> 2, sc = (t & 3) * 8;
    int bc = t & 31, bm = (t >> 5) * 16;
    int p = t >> 7;
    int wbase = bm & 63;

    for (int kc = 0; kc < 256; kc += 32) {
        const float* wrow = wp + (size_t)(otile + so) * 256 + kc + sc;
#pragma unroll
        for (int j = 0; j < 8; ++j) As[so][sc + j] = f2b(wrow[j]);
        int c = kc + bc;
        float Ac = gamma[c] * rs;
        float Dc = Ac * (blp[c] - mu) + beta[c];
        float w0 = Ac * wlp[c * 4 + p * 2 + 0];
        float w1 = Ac * wlp[c * 4 + p * 2 + 1];
        const float* arow = ao2 + ((size_t)(b * 256 + c)) * 1024 + mt * 32 + (wbase >> 1);
        float4 a0 = *(const float4*)arow;
        float4 a1 = *(const float4*)(arow + 4);
        float av[8] = {a0.x, a0.y, a0.z, a0.w, a1.x, a1.y, a1.z, a1.w};
#pragma unroll
        for (int k = 0; k < 8; ++k) {
            Bs[bm + 2 * k    ][bc] = f2b(w0 * av[k] + Dc);
            Bs[bm + 2 * k + 1][bc] = f2b(w1 * av[k] + Dc);
        }
        __syncthreads();
        bf16x8 af[2], bf_[4];
#pragma unroll
        for (int og = 0; og < 2; ++og) af[og] = *(const bf16x8*)&As[oh + og * 16 + li][8 * g];
#pragma unroll
        for (int mg = 0; mg < 4; ++mg) bf_[mg] = *(const bf16x8*)&Bs[mh + mg * 16 + li][8 * g];
#pragma unroll
        for (int og = 0; og < 2; ++og)
#pragma unroll
            for (int mg = 0; mg < 4; ++mg) acc[og][mg] = MFMA16(af[og], bf_[mg], acc[og][mg]);
        __syncthreads();
    }

#pragma unroll
    for (int og = 0; og < 2; ++og) {
        int o = otile + oh + og * 16 + 4 * g;
#pragma unroll
        for (int mg = 0; mg < 4; ++mg) {
            int m = mt * 128 + mh + mg * 16 + li;
            float* yp = y + ((size_t)b * 256 + o) * 4096 + m;
#pragma unroll
            for (int r = 0; r < 4; ++r) yp[(size_t)r * 4096] = acc[og][mg][r];
        }
    }
}

extern "C" void kernel_launch(void* const* d_in, const int* in_sizes, int n_in,
                              void* d_out, int out_size, void* d_ws, size_t ws_size,
                              hipStream_t stream) {
    const float* x      = (const float*)d_in[0];
    const float* w_qkv  = (const float*)d_in[1];
    const float* w_lp   = (const float*)d_in[2];
    const float* b_lp   = (const float*)d_in[3];
    const float* gamma  = (const float*)d_in[4];
    const float* beta   = (const float*)d_in[5];
    const float* w_proj = (const float*)d_in[6];
    float* y = (float*)d_out;

    short* qt = (short*)d_out;          // 2097152 shorts
    short* kt = qt + 2097152;
    short* vv = kt + 2097152;
    short* xt = vv + 2097152;
    short* wbuf = xt + 2097152;

    float* ao2   = (float*)d_ws;        // 2097152 floats [b][c][n]
    float* p1    = ao2 + 2097152;       // 2048
    float* p2    = p1 + 2048;           // 2048
    float* stats = p2 + 2048;           // 16

    wconv_k<<<96, 256, 0, stream>>>(w_qkv, wbuf);
    xt_k<<<dim3(32, 8), 256, 0, stream>>>(x, xt);
    qkv_k<<<dim3(8, 12, 8), 256, 0, stream>>>(wbuf, xt, qt, kt, vv);
    attn_k<<<dim3(8, 8, 8), 256, 0, stream>>>(qt, kt, vv, ao2);
    psum_k<<<2048, 64, 0, stream>>>(ao2, p1, p2);
    stats_k<<<8, 256, 0, stream>>>(p1, p2, w_lp, b_lp, stats);
    proj_k<<<dim3(32, 4, 8), 256, 0, stream>>>(ao2, w_proj, w_lp, b_lp, gamma, beta, stats, y);
}